// Round 1
// baseline (590.994 us; speedup 1.0000x reference)
//
#include <hip/hip_runtime.h>
#include <math.h>

typedef __attribute__((ext_vector_type(8))) unsigned short ushort8;
typedef __attribute__((ext_vector_type(8))) __bf16 bf16x8;
typedef __attribute__((ext_vector_type(4))) float floatx4;

constexpr int IMGW = 384;
constexpr int NPIX = IMGW * IMGW;

__device__ __forceinline__ unsigned short f2bf(float f) {
  union { float f; unsigned u; } v; v.f = f;
  unsigned u = v.u;
  return (unsigned short)((u + 0x7fffu + ((u >> 16) & 1u)) >> 16);
}
__device__ __forceinline__ float bf2f(unsigned short h) {
  union { unsigned u; float f; } v; v.u = ((unsigned)h) << 16; return v.f;
}
__device__ __forceinline__ floatx4 mfma16(bf16x8 a, bf16x8 b, floatx4 c) {
  return __builtin_amdgcn_mfma_f32_16x16x32_bf16(a, b, c, 0, 0, 0);
}
__device__ __forceinline__ bf16x8 lds_frag(const unsigned short* p) {
  return *reinterpret_cast<const bf16x8*>(p);
}

// ---------------- weight prep ----------------
// w1t[n][k] (128x64, k=63 zero-pad), w2t[n][k] (128x128), w3t[n][k] (32x128: h-part only)
__global__ void prep_mlp(const float* __restrict__ w1, const float* __restrict__ w2,
                         const float* __restrict__ w3,
                         unsigned short* __restrict__ w1t, unsigned short* __restrict__ w2t,
                         unsigned short* __restrict__ w3t) {
  int i = blockIdx.x * 256 + threadIdx.x;
  if (i < 8192) {
    int n = i >> 6, k = i & 63;
    w1t[i] = f2bf(k < 63 ? w1[k * 128 + n] : 0.0f);
  } else if (i < 8192 + 16384) {
    int j = i - 8192; int n = j >> 7, k = j & 127;
    w2t[j] = f2bf(w2[k * 128 + n]);
  } else if (i < 8192 + 16384 + 4096) {
    int j = i - 24576; int n = j >> 7, k = j & 127;
    w3t[j] = f2bf(w3[k * 32 + n]);
  }
}

// OIHW fp32 -> [O][ (ky*3+kx)*CIN + ci ] bf16
__global__ void prep_conv(const float* __restrict__ w, unsigned short* __restrict__ wt,
                          int total, int CIN) {
  int i = blockIdx.x * 256 + threadIdx.x;
  if (i >= total) return;
  int K = 9 * CIN;
  int o = i / K, k = i - o * K;
  int nb = k / CIN, ci = k - nb * CIN;
  wt[i] = f2bf(w[(o * CIN + ci) * 9 + nb]);
}

// ---------------- fused per-sample MLP ----------------
// block = 128 threads (2 waves), 64 samples. LDS layout (bytes):
//  H1 @ 0      : 64*136*2 = 17408
//  X  @ 17408  : 64*72*2  =  9216   (dead after layer1)
//  H2 @ 17408  : 17408             (reuses X region, after post-layer1 barrier)
//  dcon @34816 : 16*32*4  =  2048
//  mask @36864 : 64*4     =   256
//  dpe  @37120 : 16*28*4  =  1792   -> total 38912
__global__ __launch_bounds__(128, 2) void mlp_kernel(
    const float* __restrict__ zbufs, const float* __restrict__ ray,
    const int* __restrict__ isTrain,
    const float* __restrict__ b1, const float* __restrict__ b2,
    const float* __restrict__ b3, const float* __restrict__ w3,
    const unsigned short* __restrict__ w1t, const unsigned short* __restrict__ w2t,
    const unsigned short* __restrict__ w3t, unsigned short* __restrict__ rdmp) {
  __shared__ __align__(16) unsigned char smem[38912];
  unsigned short* H1 = (unsigned short*)(smem);
  unsigned short* X  = (unsigned short*)(smem + 17408);
  unsigned short* H2 = (unsigned short*)(smem + 17408);
  float* dcon  = (float*)(smem + 34816);
  float* maskv = (float*)(smem + 36864);
  float* dpe   = (float*)(smem + 37120);

  const int tid = threadIdx.x;
  const float thresh = (isTrain[0] != 0) ? 0.2f : 0.0f;

  // phase 0a: positional encodings
  if (tid < 64) {
    int sg = blockIdx.x * 64 + tid;
    int pixel = sg >> 2;
    float z = zbufs[sg];
    const float* r = ray + pixel * 7;
    float t = z / r[6];
    float xv[3] = { r[0] + r[3] * t, r[1] + r[4] * t, r[2] + r[5] * t };
    maskv[tid] = (z > thresh) ? 1.0f : 0.0f;
    unsigned short* Xr = X + tid * 72;
    Xr[0] = f2bf(xv[0]); Xr[1] = f2bf(xv[1]); Xr[2] = f2bf(xv[2]);
    #pragma unroll
    for (int c = 0; c < 3; ++c) {
      float fs = 1.0f;
      #pragma unroll
      for (int f = 0; f < 10; ++f) {
        float ang = xv[c] * fs;
        Xr[3 + c * 10 + f]  = f2bf(sinf(ang));
        Xr[33 + c * 10 + f] = f2bf(cosf(ang));
        fs *= 2.0f;
      }
    }
    Xr[63] = 0;
  } else if (tid < 80) {
    int pl = tid - 64;
    int pixel = blockIdx.x * 16 + pl;
    const float* r = ray + pixel * 7;
    float dv[3] = { r[3], r[4], r[5] };
    float* dp = dpe + pl * 28;
    dp[0] = dv[0]; dp[1] = dv[1]; dp[2] = dv[2];
    #pragma unroll
    for (int c = 0; c < 3; ++c) {
      float fs = 1.0f;
      #pragma unroll
      for (int f = 0; f < 4; ++f) {
        float ang = dv[c] * fs;
        dp[3 + c * 4 + f]  = sinf(ang);
        dp[15 + c * 4 + f] = cosf(ang);
        fs *= 2.0f;
      }
    }
  }
  __syncthreads();

  // phase 0b: dcon[pix][c] = b3[c] + sum_d dpe[pix][d]*w3[128+d][c]
  #pragma unroll
  for (int j = 0; j < 4; ++j) {
    int it = tid + 128 * j;          // 512 items
    int pl = it >> 5, c = it & 31;
    float dc = b3[c];
    #pragma unroll
    for (int d = 0; d < 27; ++d)
      dc += dpe[pl * 28 + d] * w3[(128 + d) * 32 + c];
    dcon[pl * 32 + c] = dc;
  }
  __syncthreads();

  const int wave = tid >> 6, lane = tid & 63, q = lane >> 4, m = lane & 15;
  const int row0 = wave * 32;

  // ---- layer 1: X(64x64) @ w1t -> H1 (relu) ----
  {
    floatx4 acc[2][8] = {};
    #pragma unroll
    for (int ks = 0; ks < 2; ++ks) {
      bf16x8 a[2];
      #pragma unroll
      for (int mt = 0; mt < 2; ++mt)
        a[mt] = lds_frag(X + (row0 + mt * 16 + m) * 72 + ks * 32 + q * 8);
      #pragma unroll
      for (int nt = 0; nt < 8; ++nt) {
        bf16x8 b = *reinterpret_cast<const bf16x8*>(w1t + (nt * 16 + m) * 64 + ks * 32 + q * 8);
        #pragma unroll
        for (int mt = 0; mt < 2; ++mt)
          acc[mt][nt] = mfma16(a[mt], b, acc[mt][nt]);
      }
    }
    #pragma unroll
    for (int mt = 0; mt < 2; ++mt)
      #pragma unroll
      for (int nt = 0; nt < 8; ++nt) {
        int col = nt * 16 + m;
        float bb = b1[col];
        #pragma unroll
        for (int r = 0; r < 4; ++r) {
          int row = row0 + mt * 16 + q * 4 + r;
          H1[row * 136 + col] = f2bf(fmaxf(acc[mt][nt][r] + bb, 0.0f));
        }
      }
  }
  __syncthreads();   // all X reads done; H2 may now overwrite X region

  // ---- layer 2: H1 @ w2t -> H2 (relu) ----
  {
    floatx4 acc[2][8] = {};
    #pragma unroll
    for (int ks = 0; ks < 4; ++ks) {
      bf16x8 a[2];
      #pragma unroll
      for (int mt = 0; mt < 2; ++mt)
        a[mt] = lds_frag(H1 + (row0 + mt * 16 + m) * 136 + ks * 32 + q * 8);
      #pragma unroll
      for (int nt = 0; nt < 8; ++nt) {
        bf16x8 b = *reinterpret_cast<const bf16x8*>(w2t + (nt * 16 + m) * 128 + ks * 32 + q * 8);
        #pragma unroll
        for (int mt = 0; mt < 2; ++mt)
          acc[mt][nt] = mfma16(a[mt], b, acc[mt][nt]);
      }
    }
    #pragma unroll
    for (int mt = 0; mt < 2; ++mt)
      #pragma unroll
      for (int nt = 0; nt < 8; ++nt) {
        int col = nt * 16 + m;
        float bb = b2[col];
        #pragma unroll
        for (int r = 0; r < 4; ++r) {
          int row = row0 + mt * 16 + q * 4 + r;
          H2[row * 136 + col] = f2bf(fmaxf(acc[mt][nt][r] + bb, 0.0f));
        }
      }
  }
  __syncthreads();

  // ---- layer 3: H2 @ w3t (+dcon) -> feat, mask, scatter to rdmp NHWC ----
  {
    floatx4 acc[2][2];
    #pragma unroll
    for (int mt = 0; mt < 2; ++mt)
      #pragma unroll
      for (int nt = 0; nt < 2; ++nt)
        #pragma unroll
        for (int r = 0; r < 4; ++r) {
          int row = row0 + mt * 16 + q * 4 + r;
          acc[mt][nt][r] = dcon[(row >> 2) * 32 + nt * 16 + m];
        }
    #pragma unroll
    for (int ks = 0; ks < 4; ++ks) {
      bf16x8 a[2];
      #pragma unroll
      for (int mt = 0; mt < 2; ++mt)
        a[mt] = lds_frag(H2 + (row0 + mt * 16 + m) * 136 + ks * 32 + q * 8);
      #pragma unroll
      for (int nt = 0; nt < 2; ++nt) {
        bf16x8 b = *reinterpret_cast<const bf16x8*>(w3t + (nt * 16 + m) * 128 + ks * 32 + q * 8);
        #pragma unroll
        for (int mt = 0; mt < 2; ++mt)
          acc[mt][nt] = mfma16(a[mt], b, acc[mt][nt]);
      }
    }
    #pragma unroll
    for (int mt = 0; mt < 2; ++mt)
      #pragma unroll
      for (int nt = 0; nt < 2; ++nt)
        #pragma unroll
        for (int r = 0; r < 4; ++r) {
          int row = row0 + mt * 16 + q * 4 + r;
          int sg = blockIdx.x * 64 + row;
          int pixel = sg >> 2, p = sg & 3;
          float v = acc[mt][nt][r] * maskv[row];
          rdmp[pixel * 128 + p * 32 + nt * 16 + m] = f2bf(v);
        }
  }
}

// ---------------- generic NHWC 3x3 conv via MFMA ----------------
// block: 256 thr, output tile 16x4 pixels, all Cout (waves split Cout).
// MODE 0: relu -> bf16 out.  MODE 1: sigmoid(acc)*rdmp -> bf16 out.
template<int CIN, int COUT, int MODE>
__global__ __launch_bounds__(256, 2) void conv3x3(
    const unsigned short* __restrict__ in, const unsigned short* __restrict__ wt,
    const float* __restrict__ bias, const unsigned short* __restrict__ rdmp,
    unsigned short* __restrict__ out) {
  constexpr int CP  = CIN + 8;       // padded pixel stride (bf16 units)
  constexpr int CH8 = CIN / 8;
  constexpr int KTOT = 9 * CIN;
  constexpr int KS = KTOT / 32;
  constexpr int NT = COUT / 64;      // 128->2 tiles/wave, 64->1
  __shared__ __align__(16) unsigned short lds_in[6 * 18 * CP];

  const int tid = threadIdx.x;
  const int x0 = blockIdx.x * 16, y0 = blockIdx.y * 4;

  for (int i = tid; i < 108 * CH8; i += 256) {
    int pix = i / CH8, part = i - pix * CH8;
    int xx = pix % 18, yy = pix / 18;
    int gx = x0 - 1 + xx, gy = y0 - 1 + yy;
    ushort8 v = {0, 0, 0, 0, 0, 0, 0, 0};
    if (gx >= 0 && gx < IMGW && gy >= 0 && gy < IMGW)
      v = *reinterpret_cast<const ushort8*>(in + ((size_t)(gy * IMGW + gx)) * CIN + part * 8);
    *reinterpret_cast<ushort8*>(&lds_in[pix * CP + part * 8]) = v;
  }
  __syncthreads();

  const int wave = tid >> 6, lane = tid & 63, q = lane >> 4, m = lane & 15;
  const int co0 = wave * (COUT / 4);
  floatx4 acc[4][NT] = {};

  for (int ks = 0; ks < KS; ++ks) {
    int nb = ks / (CIN / 32);
    int cb = (ks % (CIN / 32)) * 32 + q * 8;
    int dy = nb / 3, dx = nb - dy * 3;
    bf16x8 a[4];
    #pragma unroll
    for (int mt = 0; mt < 4; ++mt)
      a[mt] = lds_frag(&lds_in[((mt + dy) * 18 + (m + dx)) * CP + cb]);
    #pragma unroll
    for (int nt = 0; nt < NT; ++nt) {
      bf16x8 b = *reinterpret_cast<const bf16x8*>(wt + (size_t)(co0 + nt * 16 + m) * KTOT + ks * 32 + q * 8);
      #pragma unroll
      for (int mt = 0; mt < 4; ++mt)
        acc[mt][nt] = mfma16(a[mt], b, acc[mt][nt]);
    }
  }

  #pragma unroll
  for (int mt = 0; mt < 4; ++mt) {
    int y = y0 + mt;
    #pragma unroll
    for (int nt = 0; nt < NT; ++nt) {
      int co = co0 + nt * 16 + m;
      float bb = bias[co];
      #pragma unroll
      for (int r = 0; r < 4; ++r) {
        int pixel = y * IMGW + x0 + q * 4 + r;
        float v = acc[mt][nt][r] + bb;
        if (MODE == 0) {
          v = fmaxf(v, 0.0f);
        } else {
          v = 1.0f / (1.0f + __expf(-v));
          v *= bf2f(rdmp[(size_t)pixel * 128 + co]);
        }
        out[(size_t)pixel * COUT + co] = f2bf(v);
      }
    }
  }
}

// ---------------- final 64->3 conv + sigmoid, fp32 NHWC out ----------------
__global__ __launch_bounds__(256) void uconv3_kernel(
    const unsigned short* __restrict__ u2, const float* __restrict__ w,
    const float* __restrict__ b, float* __restrict__ out) {
  __shared__ float wl[1728];   // [nb][ci][c]
  for (int i = threadIdx.x; i < 1728; i += 256) {
    int c = i % 3; int t = i / 3; int ci = t & 63; int nb = t >> 6;
    wl[i] = w[(c * 64 + ci) * 9 + nb];
  }
  __syncthreads();
  int pixel = blockIdx.x * 256 + threadIdx.x;
  int py = pixel / IMGW, px = pixel - py * IMGW;
  float a0 = b[0], a1 = b[1], a2 = b[2];
  for (int nb = 0; nb < 9; ++nb) {
    int gy = py + nb / 3 - 1, gx = px + nb % 3 - 1;
    if (gx < 0 || gx >= IMGW || gy < 0 || gy >= IMGW) continue;
    const unsigned short* src = u2 + (size_t)(gy * IMGW + gx) * 64;
    const float* wp = wl + nb * 192;
    #pragma unroll
    for (int cc = 0; cc < 8; ++cc) {
      ushort8 v = *reinterpret_cast<const ushort8*>(src + cc * 8);
      #pragma unroll
      for (int j = 0; j < 8; ++j) {
        float uv = bf2f(v[j]);
        const float* w3p = wp + (cc * 8 + j) * 3;
        a0 += uv * w3p[0]; a1 += uv * w3p[1]; a2 += uv * w3p[2];
      }
    }
  }
  float* o = out + (size_t)pixel * 3;
  o[0] = 1.0f / (1.0f + __expf(-a0));
  o[1] = 1.0f / (1.0f + __expf(-a1));
  o[2] = 1.0f / (1.0f + __expf(-a2));
}

extern "C" void kernel_launch(void* const* d_in, const int* in_sizes, int n_in,
                              void* d_out, int out_size, void* d_ws, size_t ws_size,
                              hipStream_t stream) {
  (void)in_sizes; (void)n_in; (void)out_size; (void)ws_size;
  const float* zbufs = (const float*)d_in[0];
  const float* ray   = (const float*)d_in[1];
  const int* isTrain = (const int*)d_in[4];
  const float* w1 = (const float*)d_in[6];
  const float* b1 = (const float*)d_in[7];
  const float* w2 = (const float*)d_in[8];
  const float* b2 = (const float*)d_in[9];
  const float* w3 = (const float*)d_in[10];
  const float* b3 = (const float*)d_in[11];
  const float* mpn_w1 = (const float*)d_in[12];
  const float* mpn_b1 = (const float*)d_in[13];
  const float* mpn_w2 = (const float*)d_in[14];
  const float* mpn_b2 = (const float*)d_in[15];
  const float* uw1 = (const float*)d_in[16];
  const float* ub1 = (const float*)d_in[17];
  const float* uw2 = (const float*)d_in[18];
  const float* ub2 = (const float*)d_in[19];
  const float* uw3 = (const float*)d_in[20];
  const float* ub3 = (const float*)d_in[21];
  float* out = (float*)d_out;

  unsigned char* ws = (unsigned char*)d_ws;
  size_t off = 0;
  auto alloc = [&](size_t bytes) -> void* {
    void* p = ws + off; off = (off + bytes + 255) & ~(size_t)255; return p;
  };
  unsigned short* w1t  = (unsigned short*)alloc(8192 * 2);
  unsigned short* w2t  = (unsigned short*)alloc(16384 * 2);
  unsigned short* w3t  = (unsigned short*)alloc(4096 * 2);
  unsigned short* cw1  = (unsigned short*)alloc((size_t)128 * 1152 * 2);
  unsigned short* cw2  = (unsigned short*)alloc((size_t)128 * 1152 * 2);
  unsigned short* cu1  = (unsigned short*)alloc((size_t)64 * 1152 * 2);
  unsigned short* cu2  = (unsigned short*)alloc((size_t)64 * 576 * 2);
  unsigned short* rdmp = (unsigned short*)alloc((size_t)NPIX * 128 * 2);
  unsigned short* t1   = (unsigned short*)alloc((size_t)NPIX * 128 * 2);
  unsigned short* fuse = (unsigned short*)alloc((size_t)NPIX * 128 * 2);
  unsigned short* u1 = t1;     // t1 dead after conv2
  unsigned short* u2 = rdmp;   // rdmp dead after conv2 (fuse epilogue)

  prep_mlp<<<112, 256, 0, stream>>>(w1, w2, w3, w1t, w2t, w3t);
  prep_conv<<<576, 256, 0, stream>>>(mpn_w1, cw1, 128 * 1152, 128);
  prep_conv<<<576, 256, 0, stream>>>(mpn_w2, cw2, 128 * 1152, 128);
  prep_conv<<<288, 256, 0, stream>>>(uw1, cu1, 64 * 1152, 128);
  prep_conv<<<144, 256, 0, stream>>>(uw2, cu2, 64 * 576, 64);

  mlp_kernel<<<NPIX * 4 / 64, 128, 0, stream>>>(zbufs, ray, isTrain, b1, b2, b3, w3,
                                                w1t, w2t, w3t, rdmp);

  dim3 cgrid(IMGW / 16, IMGW / 4);
  conv3x3<128, 128, 0><<<cgrid, 256, 0, stream>>>(rdmp, cw1, mpn_b1, nullptr, t1);
  conv3x3<128, 128, 1><<<cgrid, 256, 0, stream>>>(t1, cw2, mpn_b2, rdmp, fuse);
  conv3x3<128, 64, 0><<<cgrid, 256, 0, stream>>>(fuse, cu1, ub1, nullptr, u1);
  conv3x3<64, 64, 0><<<cgrid, 256, 0, stream>>>(u1, cu2, ub2, nullptr, u2);
  uconv3_kernel<<<NPIX / 256, 256, 0, stream>>>(u2, uw3, ub3, out);
}